// Round 11
// baseline (331.436 us; speedup 1.0000x reference)
//
#include <hip/hip_runtime.h>

// FP8FrozenLinear: out = x @ (dequant(W)*scale)^T + bias   (W shipped as bf16/f32)
// M=8192, K=4096, N=4096.
// Round 11: R7 skeleton (256x256, BK=64, 2 LDS buffers, 1 sync/tile) with
// v_mfma_f32_32x32x16_bf16 (ceiling 2495 vs 2176 TF; half the MFMA count).
// Slab-alternating read/MFMA order for compiler partial lgkm waits.
// T2 slot swizzle kept (conflicts=0 R6-R10).

#define TILE 128
#define BKK  64
#define BM256 256
#define BN256 256

typedef __attribute__((ext_vector_type(8)))  __bf16 bfrag8;
typedef __attribute__((ext_vector_type(4)))  float  f32x4;
typedef __attribute__((ext_vector_type(16))) float  f32x16;
typedef __attribute__((ext_vector_type(8)))  short  s8v;

#define GLOBAL_AS(p) ((const __attribute__((address_space(1))) void*)(p))
#define LDS_AS(p)    ((__attribute__((address_space(3))) void*)(p))

__device__ inline unsigned short f2bf(float f) {
    union { float f; unsigned u; } v; v.f = f;
    unsigned r = v.u + 0x7FFFu + ((v.u >> 16) & 1u);   // RNE
    return (unsigned short)(r >> 16);
}
__device__ inline float bf2f(unsigned short u) {
    union { unsigned u; float f; } v; v.u = ((unsigned)u) << 16;
    return v.f;
}

// W storage dtype: f32 storage of fp8-grid values => even uint16s all zero.
__device__ inline int detect_w_f32(const void* w) {
    const unsigned short* u = (const unsigned short*)w;
    unsigned nz = 0;
#pragma unroll
    for (int i = 0; i < 64; ++i) nz |= u[2 * i];
    return nz == 0 ? 1 : 0;
}

__global__ void FP8FL_cvt_x(const float* __restrict__ x, short* __restrict__ xb, long n) {
    long i = ((long)blockIdx.x * blockDim.x + threadIdx.x) * 8;
    if (i >= n) return;
    float4 a = *(const float4*)(x + i);
    float4 b = *(const float4*)(x + i + 4);
    s8v r;
    r[0] = (short)f2bf(a.x); r[1] = (short)f2bf(a.y);
    r[2] = (short)f2bf(a.z); r[3] = (short)f2bf(a.w);
    r[4] = (short)f2bf(b.x); r[5] = (short)f2bf(b.y);
    r[6] = (short)f2bf(b.z); r[7] = (short)f2bf(b.w);
    *(s8v*)(xb + i) = r;
}

__global__ void FP8FL_cvt_w(const void* __restrict__ w, short* __restrict__ wb,
                            const float* __restrict__ scale_p, long n) {
    __shared__ int sdt;
    if (threadIdx.x == 0) sdt = detect_w_f32(w);
    __syncthreads();
    long i = ((long)blockIdx.x * blockDim.x + threadIdx.x) * 8;
    if (i >= n) return;
    const float s = scale_p[0];
    s8v r;
    if (sdt) {
        const float* wf = (const float*)w;
        float4 a = *(const float4*)(wf + i);
        float4 b = *(const float4*)(wf + i + 4);
        r[0] = (short)f2bf(a.x * s); r[1] = (short)f2bf(a.y * s);
        r[2] = (short)f2bf(a.z * s); r[3] = (short)f2bf(a.w * s);
        r[4] = (short)f2bf(b.x * s); r[5] = (short)f2bf(b.y * s);
        r[6] = (short)f2bf(b.z * s); r[7] = (short)f2bf(b.w * s);
    } else {
        const unsigned short* wu = (const unsigned short*)w;
        s8v v = *(const s8v*)(wu + i);
#pragma unroll
        for (int j = 0; j < 8; ++j)
            r[j] = (short)f2bf(bf2f((unsigned short)v[j]) * s);
    }
    *(s8v*)(wb + i) = r;
}

// ---------------- 256x256 GEMM, BK=64, dbuf, 32x32x16 MFMA ----------------
// LDS: A slab p: d*65536 + p*16384 ; B slab p: d*65536 + 32768 + p*16384.
// Slab = [256 rows][4 slots x 16B] (slot = 8 k-values), phys slot =
// logical ^ ((row>>1)&3), staged linearly with inverse-swizzled source.
__device__ inline void stage_tile256(const short* __restrict__ A, const short* __restrict__ B,
                                     long row0, long col0, int K, int kc,
                                     char* __restrict__ lds, int d, int wid, int lane) {
#pragma unroll
    for (int p = 0; p < 2; ++p) {
        char* Asl = lds + d * 65536 + p * 16384;
        char* Bsl = lds + d * 65536 + 32768 + p * 16384;
        int kk = kc + p * 32;
#pragma unroll
        for (int i = 0; i < 2; ++i) {
            int pc = i * 512 + wid * 64 + lane;
            int r  = pc >> 2;
            int j  = (pc & 3) ^ ((r >> 1) & 3);
            const short* ga = A + (size_t)(row0 + r) * K + kk + j * 8;
            const short* gb = B + (size_t)(col0 + r) * K + kk + j * 8;
            char* da = Asl + (i * 512 + wid * 64) * 16;   // wave-uniform base
            char* db = Bsl + (i * 512 + wid * 64) * 16;
            __builtin_amdgcn_global_load_lds(GLOBAL_AS(ga), LDS_AS(da), 16, 0, 0);
            __builtin_amdgcn_global_load_lds(GLOBAL_AS(gb), LDS_AS(db), 16, 0, 0);
        }
    }
}

__global__ __launch_bounds__(512, 2)
void FP8FL_gemm256(const short* __restrict__ A, const short* __restrict__ B,
                   const float* __restrict__ bias, float* __restrict__ C,
                   int M, int N, int K) {
    __shared__ char lds[131072];

    const int tid  = threadIdx.x;
    const int lane = tid & 63;
    const int wid  = tid >> 6;

    const int nwg = gridDim.x;
    const int bid = blockIdx.x;
    const int wg  = (nwg % 8 == 0) ? (bid % 8) * (nwg / 8) + (bid / 8) : bid;

    const int tiles_n = N / BN256;
    const long row0 = (long)(wg / tiles_n) * BM256;
    const long col0 = (long)(wg % tiles_n) * BN256;

    const int wm = wid >> 2, wn = wid & 3;      // 2x4 wave grid, 128x64 out each
    const int l31 = lane & 31, g2 = lane >> 5;

    // per-wave output: 4x2 tiles of 32x32
    f32x16 acc[4][2];
#pragma unroll
    for (int mt = 0; mt < 4; ++mt)
#pragma unroll
        for (int nt = 0; nt < 2; ++nt)
#pragma unroll
            for (int e = 0; e < 16; ++e) acc[mt][nt][e] = 0.f;

    const int NT = K / BKK;

    stage_tile256(A, B, row0, col0, K, 0, lds, 0, wid, lane);
    __syncthreads();

    for (int t = 0; t < NT; ++t) {
        const int d = t & 1;
        const char* Abase = lds + d * 65536;
        const char* Bbase = Abase + 32768;

#pragma unroll
        for (int p = 0; p < 2; ++p) {           // two K=32 slabs per tile
            const char* Asl = Abase + p * 16384;
            const char* Bsl = Bbase + p * 16384;

            // frag reads for this slab (both K=16 halves): 8 A + 4 B
            bfrag8 af[2][4], bfv[2][2];
#pragma unroll
            for (int k16 = 0; k16 < 2; ++k16) {
#pragma unroll
                for (int mt = 0; mt < 4; ++mt) {
                    int r  = wm * 128 + mt * 32 + l31;
                    int sl = (k16 * 2 + g2) ^ ((r >> 1) & 3);
                    af[k16][mt] = *(const bfrag8*)(Asl + (r * 4 + sl) * 16);
                }
#pragma unroll
                for (int nt = 0; nt < 2; ++nt) {
                    int r  = wn * 64 + nt * 32 + l31;
                    int sl = (k16 * 2 + g2) ^ ((r >> 1) & 3);
                    bfv[k16][nt] = *(const bfrag8*)(Bsl + (r * 4 + sl) * 16);
                }
            }

            // issue next-tile staging once, during slab 0 (full-tile latency slack)
            if (p == 0 && t + 1 < NT)
                stage_tile256(A, B, row0, col0, K, (t + 1) * BKK, lds, d ^ 1, wid, lane);

            __builtin_amdgcn_s_setprio(1);
#pragma unroll
            for (int k16 = 0; k16 < 2; ++k16)
#pragma unroll
                for (int mt = 0; mt < 4; ++mt)
#pragma unroll
                    for (int nt = 0; nt < 2; ++nt)
                        acc[mt][nt] = __builtin_amdgcn_mfma_f32_32x32x16_bf16(
                            af[k16][mt], bfv[k16][nt], acc[mt][nt], 0, 0, 0);
            __builtin_amdgcn_s_setprio(0);
        }

        __syncthreads();   // drains stage (issued a slab+ ago) + syncs buffers
    }

    // Epilogue: 32x32 C/D layout col = lane&31, row = (reg&3)+8*(reg>>2)+4*(lane>>5)  [m74/m101]
    float bv[2];
#pragma unroll
    for (int nt = 0; nt < 2; ++nt) bv[nt] = bias[col0 + wn * 64 + nt * 32 + l31];
#pragma unroll
    for (int mt = 0; mt < 4; ++mt) {
#pragma unroll
        for (int reg = 0; reg < 16; ++reg) {
            long rr = row0 + wm * 128 + mt * 32 + (reg & 3) + 8 * (reg >> 2) + 4 * g2;
            float* cp = C + rr * (long)N + col0 + wn * 64 + l31;
            cp[0]  = acc[mt][0][reg] + bv[0];
            cp[32] = acc[mt][1][reg] + bv[1];
        }
    }
}

// ---------------- m97-style 128^2 GEMM (R5, verified) — fallback ----------------
__global__ void FP8FL_gemm(const short* __restrict__ A, const short* __restrict__ B,
                           const float* __restrict__ bias, float* __restrict__ C,
                           int M, int N, int K) {
    __shared__ short As[TILE * BKK];
    __shared__ short Bs[TILE * BKK];

    const int tid  = threadIdx.x;
    const int lane = tid & 63;
    const int wid  = tid >> 6;

    const int nwg = gridDim.x;
    const int bid = blockIdx.x;
    const int wg  = (nwg % 8 == 0) ? (bid % 8) * (nwg / 8) + (bid / 8) : bid;

    const int tiles_n = N / TILE;
    const long row0 = (long)(wg / tiles_n) * TILE;
    const long col0 = (long)(wg % tiles_n) * TILE;

    const int wm = wid >> 1, wn = wid & 1;

    f32x4 acc[4][4];
#pragma unroll
    for (int i = 0; i < 4; ++i)
#pragma unroll
        for (int j = 0; j < 4; ++j) acc[i][j] = (f32x4){0.f, 0.f, 0.f, 0.f};

    const int rl = lane & 15;
    const int g  = lane >> 4;

    for (int k0 = 0; k0 < K; k0 += BKK) {
        __syncthreads();
#pragma unroll
        for (int i = 0; i < 4; ++i) {
            int c  = i * 256 + tid;
            int r  = c >> 3;
            int ls = c & 7;
            const short* ga = A + ((size_t)(row0 + r) * K + k0 + ls * 8);
            const short* gb = B + ((size_t)(col0 + r) * K + k0 + ls * 8);
            int ldsoff = (i * 256 + wid * 64) * 16;
            __builtin_amdgcn_global_load_lds(GLOBAL_AS(ga), LDS_AS((char*)As + ldsoff), 16, 0, 0);
            __builtin_amdgcn_global_load_lds(GLOBAL_AS(gb), LDS_AS((char*)Bs + ldsoff), 16, 0, 0);
        }
        __syncthreads();

#pragma unroll
        for (int kk = 0; kk < 2; ++kk) {
            bfrag8 af[4], bfr[4];
            const int lsk = kk * 4 + g;
#pragma unroll
            for (int m = 0; m < 4; ++m) {
                int r  = wm * 64 + m * 16 + rl;
                af[m] = *(const bfrag8*)&As[r * 64 + lsk * 8];
            }
#pragma unroll
            for (int n = 0; n < 4; ++n) {
                int r  = wn * 64 + n * 16 + rl;
                bfr[n] = *(const bfrag8*)&Bs[r * 64 + lsk * 8];
            }
#pragma unroll
            for (int m = 0; m < 4; ++m)
#pragma unroll
                for (int n = 0; n < 4; ++n)
                    acc[m][n] = __builtin_amdgcn_mfma_f32_16x16x32_bf16(af[m], bfr[n], acc[m][n], 0, 0, 0);
        }
    }

    float bv[4];
#pragma unroll
    for (int n = 0; n < 4; ++n) bv[n] = bias[col0 + wn * 64 + n * 16 + rl];
#pragma unroll
    for (int m = 0; m < 4; ++m) {
#pragma unroll
        for (int j = 0; j < 4; ++j) {
            long r = row0 + wm * 64 + m * 16 + g * 4 + j;
            float* cp = C + r * (long)N + col0 + wn * 64 + rl;
#pragma unroll
            for (int n = 0; n < 4; ++n) cp[n * 16] = acc[m][n][j] + bv[n];
        }
    }
}

// Fused GEMM (ws too small): reads x (f32) and W (bf16/f32) directly. R5-verified path.
__global__ void FP8FL_gemm_fused(const float* __restrict__ X, const void* __restrict__ W,
                                 const float* __restrict__ scale_p,
                                 const float* __restrict__ bias, float* __restrict__ C,
                                 int M, int N, int K) {
    __shared__ short As[TILE * BKK];
    __shared__ short Bs[TILE * BKK];
    __shared__ int sdt;

    const int tid  = threadIdx.x;
    const int lane = tid & 63;
    const int wid  = tid >> 6;

    if (tid == 0) sdt = detect_w_f32(W);
    __syncthreads();
    const int wdt = sdt;
    const float s = scale_p[0];

    const int nwg = gridDim.x;
    const int bid = blockIdx.x;
    const int wg  = (nwg % 8 == 0) ? (bid % 8) * (nwg / 8) + (bid / 8) : bid;

    const int tiles_n = N / TILE;
    const long row0 = (long)(wg / tiles_n) * TILE;
    const long col0 = (long)(wg % tiles_n) * TILE;

    const int wm = wid >> 1, wn = wid & 1;

    f32x4 acc[4][4];
#pragma unroll
    for (int i = 0; i < 4; ++i)
#pragma unroll
        for (int j = 0; j < 4; ++j) acc[i][j] = (f32x4){0.f, 0.f, 0.f, 0.f};

    const int rl = lane & 15;
    const int g  = lane >> 4;

    for (int k0 = 0; k0 < K; k0 += BKK) {
        s8v va[4], vb[4];
#pragma unroll
        for (int i = 0; i < 4; ++i) {
            int c  = i * 256 + tid;
            int r  = c >> 3;
            int ls = c & 7;
            {
                const float* xp = X + ((size_t)(row0 + r) * K + k0 + ls * 8);
                float4 a = *(const float4*)xp;
                float4 b = *(const float4*)(xp + 4);
                s8v t;
                t[0] = (short)f2bf(a.x); t[1] = (short)f2bf(a.y);
                t[2] = (short)f2bf(a.z); t[3] = (short)f2bf(a.w);
                t[4] = (short)f2bf(b.x); t[5] = (short)f2bf(b.y);
                t[6] = (short)f2bf(b.z); t[7] = (short)f2bf(b.w);
                va[i] = t;
            }
            {
                size_t off = (size_t)(col0 + r) * K + k0 + ls * 8;
                s8v t;
                if (wdt) {
                    const float* wp = (const float*)W + off;
                    float4 a = *(const float4*)wp;
                    float4 b = *(const float4*)(wp + 4);
                    t[0] = (short)f2bf(a.x * s); t[1] = (short)f2bf(a.y * s);
                    t[2] = (short)f2bf(a.z * s); t[3] = (short)f2bf(a.w * s);
                    t[4] = (short)f2bf(b.x * s); t[5] = (short)f2bf(b.y * s);
                    t[6] = (short)f2bf(b.z * s); t[7] = (short)f2bf(b.w * s);
                } else {
                    const unsigned short* wp = (const unsigned short*)W + off;
                    s8v v = *(const s8v*)wp;
#pragma unroll
                    for (int j = 0; j < 8; ++j)
                        t[j] = (short)f2bf(bf2f((unsigned short)v[j]) * s);
                }
                vb[i] = t;
            }
        }
        __syncthreads();
#pragma unroll
        for (int i = 0; i < 4; ++i) {
            int c = i * 256 + tid;
            *(s8v*)((char*)As + (size_t)c * 16) = va[i];
            *(s8v*)((char*)Bs + (size_t)c * 16) = vb[i];
        }
        __syncthreads();

#pragma unroll
        for (int kk = 0; kk < 2; ++kk) {
            bfrag8 af[4], bfr[4];
            const int lsk = kk * 4 + g;
#pragma unroll
            for (int m = 0; m < 4; ++m) {
                int r  = wm * 64 + m * 16 + rl;
                af[m] = *(const bfrag8*)&As[r * 64 + lsk * 8];
            }
#pragma unroll
            for (int n = 0; n < 4; ++n) {
                int r  = wn * 64 + n * 16 + rl;
                bfr[n] = *(const bfrag8*)&Bs[r * 64 + lsk * 8];
            }
#pragma unroll
            for (int m = 0; m < 4; ++m)
#pragma unroll
                for (int n = 0; n < 4; ++n)
                    acc[m][n] = __builtin_amdgcn_mfma_f32_16x16x32_bf16(af[m], bfr[n], acc[m][n], 0, 0, 0);
        }
    }

    float bv[4];
#pragma unroll
    for (int n = 0; n < 4; ++n) bv[n] = bias[col0 + wn * 64 + n * 16 + rl];
#pragma unroll
    for (int m = 0; m < 4; ++m) {
#pragma unroll
        for (int j = 0; j < 4; ++j) {
            long r = row0 + wm * 64 + m * 16 + g * 4 + j;
            float* cp = C + r * (long)N + col0 + wn * 64 + rl;
#pragma unroll
            for (int n = 0; n < 4; ++n) cp[n * 16] = acc[m][n][j] + bv[n];
        }
    }
}

// Last-resort fallback (odd dims).
__global__ void FP8FL_naive(const float* __restrict__ x, const void* __restrict__ w,
                            const float* __restrict__ scale_p, const float* __restrict__ bias,
                            float* __restrict__ out, int M, int N, int K) {
    __shared__ int sdt;
    if (threadIdx.x == 0) sdt = detect_w_f32(w);
    __syncthreads();
    long o = (long)blockIdx.x * blockDim.x + threadIdx.x;
    if (o >= (long)M * N) return;
    int m = (int)(o / N), n = (int)(o % N);
    const float* xr = x + (size_t)m * K;
    float acc = 0.f;
    if (sdt) {
        const float* wr = (const float*)w + (size_t)n * K;
        for (int k = 0; k < K; ++k) acc += xr[k] * wr[k];
    } else {
        const unsigned short* wr = (const unsigned short*)w + (size_t)n * K;
        for (int k = 0; k < K; ++k) acc += xr[k] * bf2f(wr[k]);
    }
    out[o] = acc * scale_p[0] + bias[n];
}

extern "C" void kernel_launch(void* const* d_in, const int* in_sizes, int n_in,
                              void* d_out, int out_size, void* d_ws, size_t ws_size,
                              hipStream_t stream) {
    const float* x     = (const float*)d_in[0];
    const void*  w     = d_in[1];
    const float* scale = (const float*)d_in[2];
    const float* bias  = (const float*)d_in[3];
    float*       out   = (float*)d_out;

    const int N = in_sizes[3];
    const int K = in_sizes[1] / N;
    const int M = in_sizes[0] / K;

    const size_t need = (size_t)M * K * 2 + (size_t)N * K * 2;
    const bool ws_ok   = ws_size >= need;
    const bool dims256 = (M % BM256 == 0) && (N % BN256 == 0) && (K % BKK == 0);
    const bool dims128 = (M % TILE == 0) && (N % TILE == 0) && (K % BKK == 0);

    if (ws_ok && (dims256 || dims128)) {
        short* xb = (short*)d_ws;
        short* wb = (short*)((char*)d_ws + (size_t)M * K * 2);
        long nx = (long)M * K;
        long nw = (long)N * K;
        FP8FL_cvt_x<<<(int)((nx / 8 + 255) / 256), 256, 0, stream>>>(x, xb, nx);
        FP8FL_cvt_w<<<(int)((nw / 8 + 255) / 256), 256, 0, stream>>>(w, wb, scale, nw);
        if (dims256) {
            int grid = (M / BM256) * (N / BN256);
            FP8FL_gemm256<<<grid, 512, 0, stream>>>(xb, wb, bias, out, M, N, K);
        } else {
            int grid = (M / TILE) * (N / TILE);
            FP8FL_gemm<<<grid, 256, 0, stream>>>(xb, wb, bias, out, M, N, K);
        }
    } else if (dims128) {
        int grid = (M / TILE) * (N / TILE);
        FP8FL_gemm_fused<<<grid, 256, 0, stream>>>(x, w, scale, bias, out, M, N, K);
    } else {
        long total = (long)M * N;
        FP8FL_naive<<<(int)((total + 255) / 256), 256, 0, stream>>>(x, w, scale, bias, out, M, N, K);
    }
}

// Round 12
// 292.105 us; speedup vs baseline: 1.1346x; 1.1346x over previous
//
#include <hip/hip_runtime.h>

// FP8FrozenLinear: out = x @ (dequant(W)*scale)^T + bias   (W shipped as bf16/f32)
// M=8192, K=4096, N=4096.
// Round 12: 256x256, BK=32, FOUR-slot LDS ring, depth-3 staging, counted
// vmcnt(4)+raw barrier per tile, and CROSS-TILE REGISTER PREFETCH of A-frags
// (read tile t+1's frags during tile t's MFMA — no dependency, pipes overlap).
// 16x16x32 MFMA (conflict-free verified pattern). Revert of R11's 32x32 shape.

#define TILE 128
#define BKK  64
#define BK32 32
#define BM256 256
#define BN256 256

typedef __attribute__((ext_vector_type(8))) __bf16 bfrag8;
typedef __attribute__((ext_vector_type(4))) float  f32x4;
typedef __attribute__((ext_vector_type(8))) short  s8v;

#define GLOBAL_AS(p) ((const __attribute__((address_space(1))) void*)(p))
#define LDS_AS(p)    ((__attribute__((address_space(3))) void*)(p))

__device__ inline unsigned short f2bf(float f) {
    union { float f; unsigned u; } v; v.f = f;
    unsigned r = v.u + 0x7FFFu + ((v.u >> 16) & 1u);   // RNE
    return (unsigned short)(r >> 16);
}
__device__ inline float bf2f(unsigned short u) {
    union { unsigned u; float f; } v; v.u = ((unsigned)u) << 16;
    return v.f;
}

// W storage dtype: f32 storage of fp8-grid values => even uint16s all zero.
__device__ inline int detect_w_f32(const void* w) {
    const unsigned short* u = (const unsigned short*)w;
    unsigned nz = 0;
#pragma unroll
    for (int i = 0; i < 64; ++i) nz |= u[2 * i];
    return nz == 0 ? 1 : 0;
}

__global__ void FP8FL_cvt_x(const float* __restrict__ x, short* __restrict__ xb, long n) {
    long i = ((long)blockIdx.x * blockDim.x + threadIdx.x) * 8;
    if (i >= n) return;
    float4 a = *(const float4*)(x + i);
    float4 b = *(const float4*)(x + i + 4);
    s8v r;
    r[0] = (short)f2bf(a.x); r[1] = (short)f2bf(a.y);
    r[2] = (short)f2bf(a.z); r[3] = (short)f2bf(a.w);
    r[4] = (short)f2bf(b.x); r[5] = (short)f2bf(b.y);
    r[6] = (short)f2bf(b.z); r[7] = (short)f2bf(b.w);
    *(s8v*)(xb + i) = r;
}

__global__ void FP8FL_cvt_w(const void* __restrict__ w, short* __restrict__ wb,
                            const float* __restrict__ scale_p, long n) {
    __shared__ int sdt;
    if (threadIdx.x == 0) sdt = detect_w_f32(w);
    __syncthreads();
    long i = ((long)blockIdx.x * blockDim.x + threadIdx.x) * 8;
    if (i >= n) return;
    const float s = scale_p[0];
    s8v r;
    if (sdt) {
        const float* wf = (const float*)w;
        float4 a = *(const float4*)(wf + i);
        float4 b = *(const float4*)(wf + i + 4);
        r[0] = (short)f2bf(a.x * s); r[1] = (short)f2bf(a.y * s);
        r[2] = (short)f2bf(a.z * s); r[3] = (short)f2bf(a.w * s);
        r[4] = (short)f2bf(b.x * s); r[5] = (short)f2bf(b.y * s);
        r[6] = (short)f2bf(b.z * s); r[7] = (short)f2bf(b.w * s);
    } else {
        const unsigned short* wu = (const unsigned short*)w;
        s8v v = *(const s8v*)(wu + i);
#pragma unroll
        for (int j = 0; j < 8; ++j)
            r[j] = (short)f2bf(bf2f((unsigned short)v[j]) * s);
    }
    *(s8v*)(wb + i) = r;
}

// ---------------- 256x256 GEMM, BK=32, 4-ring, cross-tile reg prefetch ----------------
// Ring slot s at lds + s*32768: A slab 16KB ([256 rows][4 slots x16B]) then
// B slab 16KB. phys slot = logical ^ ((r>>1)&3); staged linearly with
// inverse-swizzled source (rule #21; conflicts=0 for 16x16 reads, R6-R10).
// Per thread per tile: 4 global_load_lds (2 A + 2 B).
__device__ inline void stage_tile4(const short* __restrict__ A, const short* __restrict__ B,
                                   long row0, long col0, int K, int kc,
                                   char* __restrict__ lds, int s, int wid, int lane) {
    char* Asl = lds + s * 32768;
    char* Bsl = Asl + 16384;
#pragma unroll
    for (int i = 0; i < 2; ++i) {
        int pc = i * 512 + wid * 64 + lane;      // chunk 0..1023 per matrix
        int r  = pc >> 2;
        int j  = (pc & 3) ^ ((r >> 1) & 3);
        const short* ga = A + (size_t)(row0 + r) * K + kc + j * 8;
        const short* gb = B + (size_t)(col0 + r) * K + kc + j * 8;
        char* da = Asl + (i * 512 + wid * 64) * 16;   // wave-uniform base
        char* db = Bsl + (i * 512 + wid * 64) * 16;
        __builtin_amdgcn_global_load_lds(GLOBAL_AS(ga), LDS_AS(da), 16, 0, 0);
        __builtin_amdgcn_global_load_lds(GLOBAL_AS(gb), LDS_AS(db), 16, 0, 0);
    }
}

#define RD_A(dst, sbase)                                                    \
    {                                                                       \
        _Pragma("unroll")                                                   \
        for (int m = 0; m < 8; ++m) {                                       \
            int r  = wm * 128 + m * 16 + rl;                                \
            int sl = g ^ ((r >> 1) & 3);                                    \
            dst[m] = *(const bfrag8*)((sbase) + (r * 4 + sl) * 16);         \
        }                                                                   \
    }

#define RD_B(dst, sbase)                                                    \
    {                                                                       \
        _Pragma("unroll")                                                   \
        for (int n = 0; n < 4; ++n) {                                       \
            int r  = wn * 64 + n * 16 + rl;                                 \
            int sl = g ^ ((r >> 1) & 3);                                    \
            dst[n] = *(const bfrag8*)((sbase) + 16384 + (r * 4 + sl) * 16); \
        }                                                                   \
    }

#define MM(fa, bb)                                                          \
    {                                                                       \
        __builtin_amdgcn_s_setprio(1);                                      \
        _Pragma("unroll")                                                   \
        for (int m = 0; m < 8; ++m)                                         \
            _Pragma("unroll")                                               \
            for (int n = 0; n < 4; ++n)                                     \
                acc[m][n] = __builtin_amdgcn_mfma_f32_16x16x32_bf16(        \
                    fa[m], bb[n], acc[m][n], 0, 0, 0);                      \
        __builtin_amdgcn_s_setprio(0);                                      \
    }

__global__ __launch_bounds__(512, 2)
void FP8FL_gemm256(const short* __restrict__ A, const short* __restrict__ B,
                   const float* __restrict__ bias, float* __restrict__ C,
                   int M, int N, int K) {
    __shared__ char lds[4 * 32768];

    const int tid  = threadIdx.x;
    const int lane = tid & 63;
    const int wid  = tid >> 6;

    const int nwg = gridDim.x;
    const int bid = blockIdx.x;
    const int wg  = (nwg % 8 == 0) ? (bid % 8) * (nwg / 8) + (bid / 8) : bid;

    const int tiles_n = N / BN256;
    const long row0 = (long)(wg / tiles_n) * BM256;
    const long col0 = (long)(wg % tiles_n) * BN256;

    const int wm = wid >> 2, wn = wid & 3;      // 2x4 wave grid, 128x64 out each
    const int rl = lane & 15, g = lane >> 4;

    f32x4 acc[8][4];
#pragma unroll
    for (int m = 0; m < 8; ++m)
#pragma unroll
        for (int n = 0; n < 4; ++n) acc[m][n] = (f32x4){0.f, 0.f, 0.f, 0.f};

    const int NT = K / BK32;   // >= 4, even (guarded by launcher)

    // Prologue: stage tiles 0,1,2 (depth-3); tiles 0,1 landed after vmcnt(4).
    stage_tile4(A, B, row0, col0, K, 0,        lds, 0, wid, lane);
    stage_tile4(A, B, row0, col0, K, BK32,     lds, 1, wid, lane);
    stage_tile4(A, B, row0, col0, K, 2 * BK32, lds, 2, wid, lane);
    asm volatile("s_waitcnt vmcnt(4)" ::: "memory");
    __builtin_amdgcn_s_barrier();

    bfrag8 FA[8], FB[8], BB[4];
    RD_A(FA, lds);             // tile 0 A-frags (slot 0)

    for (int t = 0; t < NT; t += 2) {
        // ---- even: compute tile t (FA); prefetch A-frags of t+1 (landed) ----
        if (t + 3 < NT)
            stage_tile4(A, B, row0, col0, K, (t + 3) * BK32, lds, (t + 3) & 3, wid, lane);
        RD_A(FB, lds + ((t + 1) & 3) * 32768);   // no dep on MM below -> overlaps
        RD_B(BB, lds + (t & 3) * 32768);
        MM(FA, BB);
        if (t + 3 < NT) asm volatile("s_waitcnt vmcnt(4)" ::: "memory");
        else            asm volatile("s_waitcnt vmcnt(0)" ::: "memory");
        __builtin_amdgcn_s_barrier();

        // ---- odd: compute tile t+1 (FB); prefetch A-frags of t+2 ----
        if (t + 4 < NT)
            stage_tile4(A, B, row0, col0, K, (t + 4) * BK32, lds, (t + 4) & 3, wid, lane);
        if (t + 2 < NT)
            RD_A(FA, lds + ((t + 2) & 3) * 32768);
        RD_B(BB, lds + ((t + 1) & 3) * 32768);
        MM(FB, BB);
        if (t + 4 < NT) asm volatile("s_waitcnt vmcnt(4)" ::: "memory");
        else            asm volatile("s_waitcnt vmcnt(0)" ::: "memory");
        __builtin_amdgcn_s_barrier();
    }

    // Epilogue: C/D layout col = lane&15, row = (lane>>4)*4 + reg  [m89/m91]
    float bv[4];
#pragma unroll
    for (int n = 0; n < 4; ++n) bv[n] = bias[col0 + wn * 64 + n * 16 + rl];
#pragma unroll
    for (int m = 0; m < 8; ++m) {
#pragma unroll
        for (int jj = 0; jj < 4; ++jj) {
            long r = row0 + wm * 128 + m * 16 + g * 4 + jj;
            float* cp = C + r * (long)N + col0 + wn * 64 + rl;
#pragma unroll
            for (int n = 0; n < 4; ++n) cp[n * 16] = acc[m][n][jj] + bv[n];
        }
    }
}

// ---------------- m97-style 128^2 GEMM (R5, verified) — fallback ----------------
__global__ void FP8FL_gemm(const short* __restrict__ A, const short* __restrict__ B,
                           const float* __restrict__ bias, float* __restrict__ C,
                           int M, int N, int K) {
    __shared__ short As[TILE * BKK];
    __shared__ short Bs[TILE * BKK];

    const int tid  = threadIdx.x;
    const int lane = tid & 63;
    const int wid  = tid >> 6;

    const int nwg = gridDim.x;
    const int bid = blockIdx.x;
    const int wg  = (nwg % 8 == 0) ? (bid % 8) * (nwg / 8) + (bid / 8) : bid;

    const int tiles_n = N / TILE;
    const long row0 = (long)(wg / tiles_n) * TILE;
    const long col0 = (long)(wg % tiles_n) * TILE;

    const int wm = wid >> 1, wn = wid & 1;

    f32x4 acc[4][4];
#pragma unroll
    for (int i = 0; i < 4; ++i)
#pragma unroll
        for (int j = 0; j < 4; ++j) acc[i][j] = (f32x4){0.f, 0.f, 0.f, 0.f};

    const int rl = lane & 15;
    const int g  = lane >> 4;

    for (int k0 = 0; k0 < K; k0 += BKK) {
        __syncthreads();
#pragma unroll
        for (int i = 0; i < 4; ++i) {
            int c  = i * 256 + tid;
            int r  = c >> 3;
            int ls = c & 7;
            const short* ga = A + ((size_t)(row0 + r) * K + k0 + ls * 8);
            const short* gb = B + ((size_t)(col0 + r) * K + k0 + ls * 8);
            int ldsoff = (i * 256 + wid * 64) * 16;
            __builtin_amdgcn_global_load_lds(GLOBAL_AS(ga), LDS_AS((char*)As + ldsoff), 16, 0, 0);
            __builtin_amdgcn_global_load_lds(GLOBAL_AS(gb), LDS_AS((char*)Bs + ldsoff), 16, 0, 0);
        }
        __syncthreads();

#pragma unroll
        for (int kk = 0; kk < 2; ++kk) {
            bfrag8 af[4], bfr[4];
            const int lsk = kk * 4 + g;
#pragma unroll
            for (int m = 0; m < 4; ++m) {
                int r  = wm * 64 + m * 16 + rl;
                af[m] = *(const bfrag8*)&As[r * 64 + lsk * 8];
            }
#pragma unroll
            for (int n = 0; n < 4; ++n) {
                int r  = wn * 64 + n * 16 + rl;
                bfr[n] = *(const bfrag8*)&Bs[r * 64 + lsk * 8];
            }
#pragma unroll
            for (int m = 0; m < 4; ++m)
#pragma unroll
                for (int n = 0; n < 4; ++n)
                    acc[m][n] = __builtin_amdgcn_mfma_f32_16x16x32_bf16(af[m], bfr[n], acc[m][n], 0, 0, 0);
        }
    }

    float bv[4];
#pragma unroll
    for (int n = 0; n < 4; ++n) bv[n] = bias[col0 + wn * 64 + n * 16 + rl];
#pragma unroll
    for (int m = 0; m < 4; ++m) {
#pragma unroll
        for (int j = 0; j < 4; ++j) {
            long r = row0 + wm * 64 + m * 16 + g * 4 + j;
            float* cp = C + r * (long)N + col0 + wn * 64 + rl;
#pragma unroll
            for (int n = 0; n < 4; ++n) cp[n * 16] = acc[m][n][j] + bv[n];
        }
    }
}

// Fused GEMM (ws too small): reads x (f32) and W (bf16/f32) directly. R5-verified path.
__global__ void FP8FL_gemm_fused(const float* __restrict__ X, const void* __restrict__ W,
                                 const float* __restrict__ scale_p,
                                 const float* __restrict__ bias, float* __restrict__ C,
                                 int M, int N, int K) {
    __shared__ short As[TILE * BKK];
    __shared__ short Bs[TILE * BKK];
    __shared__ int sdt;

    const int tid  = threadIdx.x;
    const int lane = tid & 63;
    const int wid  = tid >> 6;

    if (tid == 0) sdt = detect_w_f32(W);
    __syncthreads();
    const int wdt = sdt;
    const float s = scale_p[0];

    const int nwg = gridDim.x;
    const int bid = blockIdx.x;
    const int wg  = (nwg % 8 == 0) ? (bid % 8) * (nwg / 8) + (bid / 8) : bid;

    const int tiles_n = N / TILE;
    const long row0 = (long)(wg / tiles_n) * TILE;
    const long col0 = (long)(wg % tiles_n) * TILE;

    const int wm = wid >> 1, wn = wid & 1;

    f32x4 acc[4][4];
#pragma unroll
    for (int i = 0; i < 4; ++i)
#pragma unroll
        for (int j = 0; j < 4; ++j) acc[i][j] = (f32x4){0.f, 0.f, 0.f, 0.f};

    const int rl = lane & 15;
    const int g  = lane >> 4;

    for (int k0 = 0; k0 < K; k0 += BKK) {
        s8v va[4], vb[4];
#pragma unroll
        for (int i = 0; i < 4; ++i) {
            int c  = i * 256 + tid;
            int r  = c >> 3;
            int ls = c & 7;
            {
                const float* xp = X + ((size_t)(row0 + r) * K + k0 + ls * 8);
                float4 a = *(const float4*)xp;
                float4 b = *(const float4*)(xp + 4);
                s8v t;
                t[0] = (short)f2bf(a.x); t[1] = (short)f2bf(a.y);
                t[2] = (short)f2bf(a.z); t[3] = (short)f2bf(a.w);
                t[4] = (short)f2bf(b.x); t[5] = (short)f2bf(b.y);
                t[6] = (short)f2bf(b.z); t[7] = (short)f2bf(b.w);
                va[i] = t;
            }
            {
                size_t off = (size_t)(col0 + r) * K + k0 + ls * 8;
                s8v t;
                if (wdt) {
                    const float* wp = (const float*)W + off;
                    float4 a = *(const float4*)wp;
                    float4 b = *(const float4*)(wp + 4);
                    t[0] = (short)f2bf(a.x * s); t[1] = (short)f2bf(a.y * s);
                    t[2] = (short)f2bf(a.z * s); t[3] = (short)f2bf(a.w * s);
                    t[4] = (short)f2bf(b.x * s); t[5] = (short)f2bf(b.y * s);
                    t[6] = (short)f2bf(b.z * s); t[7] = (short)f2bf(b.w * s);
                } else {
                    const unsigned short* wp = (const unsigned short*)W + off;
                    s8v v = *(const s8v*)wp;
#pragma unroll
                    for (int j = 0; j < 8; ++j)
                        t[j] = (short)f2bf(bf2f((unsigned short)v[j]) * s);
                }
                vb[i] = t;
            }
        }
        __syncthreads();
#pragma unroll
        for (int i = 0; i < 4; ++i) {
            int c = i * 256 + tid;
            *(s8v*)((char*)As + (size_t)c * 16) = va[i];
            *(s8v*)((char*)Bs + (size_t)c * 16) = vb[i];
        }
        __syncthreads();

#pragma unroll
        for (int kk = 0; kk < 2; ++kk) {
            bfrag8 af[4], bfr[4];
            const int lsk = kk * 4 + g;
#pragma unroll
            for (int m = 0; m < 4; ++m) {
                int r  = wm * 64 + m * 16 + rl;
                af[m] = *(const bfrag8*)&As[r * 64 + lsk * 8];
            }
#pragma unroll
            for (int n = 0; n < 4; ++n) {
                int r  = wn * 64 + n * 16 + rl;
                bfr[n] = *(const bfrag8*)&Bs[r * 64 + lsk * 8];
            }
#pragma unroll
            for (int m = 0; m < 4; ++m)
#pragma unroll
                for (int n = 0; n < 4; ++n)
                    acc[m][n] = __builtin_amdgcn_mfma_f32_16x16x32_bf16(af[m], bfr[n], acc[m][n], 0, 0, 0);
        }
    }

    float bv[4];
#pragma unroll
    for (int n = 0; n < 4; ++n) bv[n] = bias[col0 + wn * 64 + n * 16 + rl];
#pragma unroll
    for (int m = 0; m < 4; ++m) {
#pragma unroll
        for (int j = 0; j < 4; ++j) {
            long r = row0 + wm * 64 + m * 16 + g * 4 + j;
            float* cp = C + r * (long)N + col0 + wn * 64 + rl;
#pragma unroll
            for (int n = 0; n < 4; ++n) cp[n * 16] = acc[m][n][j] + bv[n];
        }
    }
}

// Last-resort fallback (odd dims).
__global__ void FP8FL_naive(const float* __restrict__ x, const void* __restrict__ w,
                            const float* __restrict__ scale_p, const float* __restrict__ bias,
                            float* __restrict__ out, int M, int N, int K) {
    __shared__ int sdt;
    if (threadIdx.x == 0) sdt = detect_w_f32(w);
    __syncthreads();
    long o = (long)blockIdx.x * blockDim.x + threadIdx.x;
    if (o >= (long)M * N) return;
    int m = (int)(o / N), n = (int)(o % N);
    const float* xr = x + (size_t)m * K;
    float acc = 0.f;
    if (sdt) {
        const float* wr = (const float*)w + (size_t)n * K;
        for (int k = 0; k < K; ++k) acc += xr[k] * wr[k];
    } else {
        const unsigned short* wr = (const unsigned short*)w + (size_t)n * K;
        for (int k = 0; k < K; ++k) acc += xr[k] * bf2f(wr[k]);
    }
    out[o] = acc * scale_p[0] + bias[n];
}

extern "C" void kernel_launch(void* const* d_in, const int* in_sizes, int n_in,
                              void* d_out, int out_size, void* d_ws, size_t ws_size,
                              hipStream_t stream) {
    const float* x     = (const float*)d_in[0];
    const void*  w     = d_in[1];
    const float* scale = (const float*)d_in[2];
    const float* bias  = (const float*)d_in[3];
    float*       out   = (float*)d_out;

    const int N = in_sizes[3];
    const int K = in_sizes[1] / N;
    const int M = in_sizes[0] / K;

    const size_t need = (size_t)M * K * 2 + (size_t)N * K * 2;
    const bool ws_ok   = ws_size >= need;
    const bool dims256 = (M % BM256 == 0) && (N % BN256 == 0) && (K % BKK == 0) && (K / BK32 >= 4);
    const bool dims128 = (M % TILE == 0) && (N % TILE == 0) && (K % BKK == 0);

    if (ws_ok && (dims256 || dims128)) {
        short* xb = (short*)d_ws;
        short* wb = (short*)((char*)d_ws + (size_t)M * K * 2);
        long nx = (long)M * K;
        long nw = (long)N * K;
        FP8FL_cvt_x<<<(int)((nx / 8 + 255) / 256), 256, 0, stream>>>(x, xb, nx);
        FP8FL_cvt_w<<<(int)((nw / 8 + 255) / 256), 256, 0, stream>>>(w, wb, scale, nw);
        if (dims256) {
            int grid = (M / BM256) * (N / BN256);
            FP8FL_gemm256<<<grid, 512, 0, stream>>>(xb, wb, bias, out, M, N, K);
        } else {
            int grid = (M / TILE) * (N / TILE);
            FP8FL_gemm<<<grid, 256, 0, stream>>>(xb, wb, bias, out, M, N, K);
        }
    } else if (dims128) {
        int grid = (M / TILE) * (N / TILE);
        FP8FL_gemm_fused<<<grid, 256, 0, stream>>>(x, w, scale, bias, out, M, N, K);
    } else {
        long total = (long)M * N;
        FP8FL_naive<<<(int)((total + 255) / 256), 256, 0, stream>>>(x, w, scale, bias, out, M, N, K);
    }
}

// Round 13
// 289.088 us; speedup vs baseline: 1.1465x; 1.0104x over previous
//
#include <hip/hip_runtime.h>

// FP8FrozenLinear: out = x @ (dequant(W)*scale)^T + bias   (W shipped as bf16/f32)
// M=8192, K=4096, N=4096.
// Round 13: faithful quadrant-phase pipeline (m201 mechanism re-derived).
// 256x256, BK=64, LDS = 2 bufs x 4 halves x 16KB = 128KB.
// Halves: A0=[rows 0..127], A1=[128..255] of the A-tile; B0/B1 same for W.
// Phases per K-tile: P0(mh0,nh0) P1(mh0,nh1) P2(mh1,nh1) P3(mh1,nh0).
// Per phase: {ds_read new frags | stage one half of tile t+1 | bar | lgkm0 |
// setprio(1) 16 MFMA setprio(0) | counted vmcnt | bar}.
// Waits: vmcnt(2) end-P0, vmcnt(4) end-P3 (never 0 in-loop).
// Proof: A0(t),B0(t) staged (t-1).P0/P1 -> landed by (t-1).P3's vmcnt(4)
// (only A1(t),B1(t)=4 loads newer). B1(t) staged (t-1).P3 -> landed by
// t.P0's vmcnt(2) (only A0(t+1)=2 loads newer). A1(t) older than B1(t) ->
// transitively landed. Overwrites: each half's stage is >=4 barriers after
// its last ds_read. Frag regs: A held 2 phases, B0 held 4, B1 held 2.

#define TILE 128
#define BKK  64
#define BM256 256
#define BN256 256

typedef __attribute__((ext_vector_type(8))) __bf16 bfrag8;
typedef __attribute__((ext_vector_type(4))) float  f32x4;
typedef __attribute__((ext_vector_type(8))) short  s8v;

#define GLOBAL_AS(p) ((const __attribute__((address_space(1))) void*)(p))
#define LDS_AS(p)    ((__attribute__((address_space(3))) void*)(p))

__device__ inline unsigned short f2bf(float f) {
    union { float f; unsigned u; } v; v.f = f;
    unsigned r = v.u + 0x7FFFu + ((v.u >> 16) & 1u);   // RNE
    return (unsigned short)(r >> 16);
}
__device__ inline float bf2f(unsigned short u) {
    union { unsigned u; float f; } v; v.u = ((unsigned)u) << 16;
    return v.f;
}

// W storage dtype: f32 storage of fp8-grid values => even uint16s all zero.
__device__ inline int detect_w_f32(const void* w) {
    const unsigned short* u = (const unsigned short*)w;
    unsigned nz = 0;
#pragma unroll
    for (int i = 0; i < 64; ++i) nz |= u[2 * i];
    return nz == 0 ? 1 : 0;
}

__global__ void FP8FL_cvt_x(const float* __restrict__ x, short* __restrict__ xb, long n) {
    long i = ((long)blockIdx.x * blockDim.x + threadIdx.x) * 8;
    if (i >= n) return;
    float4 a = *(const float4*)(x + i);
    float4 b = *(const float4*)(x + i + 4);
    s8v r;
    r[0] = (short)f2bf(a.x); r[1] = (short)f2bf(a.y);
    r[2] = (short)f2bf(a.z); r[3] = (short)f2bf(a.w);
    r[4] = (short)f2bf(b.x); r[5] = (short)f2bf(b.y);
    r[6] = (short)f2bf(b.z); r[7] = (short)f2bf(b.w);
    *(s8v*)(xb + i) = r;
}

__global__ void FP8FL_cvt_w(const void* __restrict__ w, short* __restrict__ wb,
                            const float* __restrict__ scale_p, long n) {
    __shared__ int sdt;
    if (threadIdx.x == 0) sdt = detect_w_f32(w);
    __syncthreads();
    long i = ((long)blockIdx.x * blockDim.x + threadIdx.x) * 8;
    if (i >= n) return;
    const float s = scale_p[0];
    s8v r;
    if (sdt) {
        const float* wf = (const float*)w;
        float4 a = *(const float4*)(wf + i);
        float4 b = *(const float4*)(wf + i + 4);
        r[0] = (short)f2bf(a.x * s); r[1] = (short)f2bf(a.y * s);
        r[2] = (short)f2bf(a.z * s); r[3] = (short)f2bf(a.w * s);
        r[4] = (short)f2bf(b.x * s); r[5] = (short)f2bf(b.y * s);
        r[6] = (short)f2bf(b.z * s); r[7] = (short)f2bf(b.w * s);
    } else {
        const unsigned short* wu = (const unsigned short*)w;
        s8v v = *(const s8v*)(wu + i);
#pragma unroll
        for (int j = 0; j < 8; ++j)
            r[j] = (short)f2bf(bf2f((unsigned short)v[j]) * s);
    }
    *(s8v*)(wb + i) = r;
}

// ---- quadrant-phase 256x256 kernel helpers ----
// Half layout: [128 rows][8 slots x 16B], phys slot = logical ^ (row & 7).
// Stage one half (16 KB): 1024 chunks, 2/thread, linear LDS dest,
// inverse-swizzled global source (rule #21 both-sides involution).
#define STG(P, base0, hrow, kc, dst)                                          \
    {                                                                         \
        _Pragma("unroll")                                                     \
        for (int i_ = 0; i_ < 2; ++i_) {                                      \
            int pc_ = i_ * 512 + tid;                                         \
            int r_  = pc_ >> 3;                                               \
            int j_  = (pc_ & 7) ^ (r_ & 7);                                   \
            const short* gp_ = (P) + (size_t)((base0) + (hrow) + r_) * K + (kc) + j_ * 8; \
            char* dp_ = (dst) + (i_ * 512 + wid * 64) * 16;                   \
            __builtin_amdgcn_global_load_lds(GLOBAL_AS(gp_), LDS_AS(dp_), 16, 0, 0); \
        }                                                                     \
    }

#define RD_A8(dst, half)                                                      \
    {                                                                         \
        _Pragma("unroll")                                                     \
        for (int mf_ = 0; mf_ < 4; ++mf_)                                     \
            _Pragma("unroll")                                                 \
            for (int kk_ = 0; kk_ < 2; ++kk_) {                               \
                int r_  = wm * 64 + mf_ * 16 + rl;                            \
                int sl_ = (kk_ * 4 + g) ^ (r_ & 7);                           \
                dst[mf_ * 2 + kk_] = *(const bfrag8*)((half) + (r_ * 8 + sl_) * 16); \
            }                                                                 \
    }

#define RD_B4(dst, half)                                                      \
    {                                                                         \
        _Pragma("unroll")                                                     \
        for (int nf_ = 0; nf_ < 2; ++nf_)                                     \
            _Pragma("unroll")                                                 \
            for (int kk_ = 0; kk_ < 2; ++kk_) {                               \
                int r_  = wn * 32 + nf_ * 16 + rl;                            \
                int sl_ = (kk_ * 4 + g) ^ (r_ & 7);                           \
                dst[nf_ * 2 + kk_] = *(const bfrag8*)((half) + (r_ * 8 + sl_) * 16); \
            }                                                                 \
    }

#define MM16(mh, nh, FAa, FBb)                                                \
    {                                                                         \
        __builtin_amdgcn_s_setprio(1);                                        \
        _Pragma("unroll")                                                     \
        for (int mf_ = 0; mf_ < 4; ++mf_)                                     \
            _Pragma("unroll")                                                 \
            for (int nf_ = 0; nf_ < 2; ++nf_)                                 \
                _Pragma("unroll")                                             \
                for (int kk_ = 0; kk_ < 2; ++kk_)                             \
                    acc[mh][nh][mf_][nf_] = __builtin_amdgcn_mfma_f32_16x16x32_bf16( \
                        FAa[mf_ * 2 + kk_], FBb[nf_ * 2 + kk_],               \
                        acc[mh][nh][mf_][nf_], 0, 0, 0);                      \
        __builtin_amdgcn_s_setprio(0);                                        \
    }

#define LGKM0_FENCE                                                           \
    asm volatile("s_waitcnt lgkmcnt(0)" ::: "memory");                        \
    __builtin_amdgcn_sched_barrier(0);

__global__ __launch_bounds__(512, 2)
void FP8FL_gemm256(const short* __restrict__ A, const short* __restrict__ B,
                   const float* __restrict__ bias, float* __restrict__ C,
                   int M, int N, int K) {
    __shared__ char lds[131072];   // buf d: +d*65536; A0 +0, A1 +16384, B0 +32768, B1 +49152

    const int tid  = threadIdx.x;
    const int lane = tid & 63;
    const int wid  = tid >> 6;

    const int nwg = gridDim.x;
    const int bid = blockIdx.x;
    const int wg  = (nwg % 8 == 0) ? (bid % 8) * (nwg / 8) + (bid / 8) : bid;

    const int tiles_n = N / BN256;
    const long row0 = (long)(wg / tiles_n) * BM256;
    const long col0 = (long)(wg % tiles_n) * BN256;

    const int wm = wid >> 2, wn = wid & 3;      // 2x4 wave grid
    const int rl = lane & 15, g = lane >> 4;

    // acc[mh][nh][mf][nf]: wave's C rows = mh*128 + wm*64 + mf*16 + ...,
    // cols = nh*128 + wn*32 + nf*16 + ...   (128 VGPR)
    f32x4 acc[2][2][4][2];
#pragma unroll
    for (int a0 = 0; a0 < 2; ++a0)
#pragma unroll
        for (int a1 = 0; a1 < 2; ++a1)
#pragma unroll
            for (int a2 = 0; a2 < 4; ++a2)
#pragma unroll
                for (int a3 = 0; a3 < 2; ++a3)
                    acc[a0][a1][a2][a3] = (f32x4){0.f, 0.f, 0.f, 0.f};

    const int NT = K / BKK;

    // Prologue: stage all 4 halves of tile 0 into buf0; A0,B0 must land.
    {
        char* b0 = lds;
        STG(A, row0, 0,   0, b0 + 0);
        STG(B, col0, 0,   0, b0 + 32768);
        STG(A, row0, 128, 0, b0 + 16384);
        STG(B, col0, 128, 0, b0 + 49152);
    }
    asm volatile("s_waitcnt vmcnt(4)" ::: "memory");
    __builtin_amdgcn_s_barrier();

    bfrag8 FA[8], FB0[4], FB1[4];

    for (int t = 0; t < NT; ++t) {
        char* cur = lds + (t & 1) * 65536;
        char* nxt = lds + ((t + 1) & 1) * 65536;
        const int kc1 = (t + 1) * BKK;
        const bool pf = (t + 1 < NT);

        // ---- P0: quadrant (mh0, nh0); stage A0(t+1) ----
        RD_A8(FA, cur + 0);            // A0
        RD_B4(FB0, cur + 32768);       // B0 (held through P3)
        if (pf) STG(A, row0, 0, kc1, nxt + 0);
        __builtin_amdgcn_s_barrier();
        LGKM0_FENCE
        MM16(0, 0, FA, FB0);
        if (pf) asm volatile("s_waitcnt vmcnt(2)" ::: "memory");
        else    asm volatile("s_waitcnt vmcnt(0)" ::: "memory");
        __builtin_amdgcn_s_barrier();

        // ---- P1: quadrant (mh0, nh1); stage B0(t+1) ----
        RD_B4(FB1, cur + 49152);       // B1
        if (pf) STG(B, col0, 0, kc1, nxt + 32768);
        __builtin_amdgcn_s_barrier();
        LGKM0_FENCE
        MM16(0, 1, FA, FB1);
        __builtin_amdgcn_s_barrier();

        // ---- P2: quadrant (mh1, nh1); stage A1(t+1) ----
        RD_A8(FA, cur + 16384);        // A1 (overwrites FA)
        if (pf) STG(A, row0, 128, kc1, nxt + 16384);
        __builtin_amdgcn_s_barrier();
        LGKM0_FENCE
        MM16(1, 1, FA, FB1);
        __builtin_amdgcn_s_barrier();

        // ---- P3: quadrant (mh1, nh0); stage B1(t+1); no new reads ----
        if (pf) STG(B, col0, 128, kc1, nxt + 49152);
        __builtin_amdgcn_s_barrier();
        MM16(1, 0, FA, FB0);
        if (pf) asm volatile("s_waitcnt vmcnt(4)" ::: "memory");
        __builtin_amdgcn_s_barrier();
    }

    // Epilogue: C/D 16x16 layout col=lane&15, row=(lane>>4)*4+reg  [m89/m91]
    float bv[2][2];
#pragma unroll
    for (int nh = 0; nh < 2; ++nh)
#pragma unroll
        for (int nf = 0; nf < 2; ++nf)
            bv[nh][nf] = bias[col0 + nh * 128 + wn * 32 + nf * 16 + rl];
#pragma unroll
    for (int mh = 0; mh < 2; ++mh)
#pragma unroll
        for (int mf = 0; mf < 4; ++mf)
#pragma unroll
            for (int jj = 0; jj < 4; ++jj) {
                long r = row0 + mh * 128 + wm * 64 + mf * 16 + g * 4 + jj;
                float* cp = C + r * (long)N + col0 + wn * 32 + rl;
#pragma unroll
                for (int nh = 0; nh < 2; ++nh)
#pragma unroll
                    for (int nf = 0; nf < 2; ++nf)
                        cp[nh * 128 + nf * 16] = acc[mh][nh][mf][nf][jj] + bv[nh][nf];
            }
}

// ---------------- m97-style 128^2 GEMM (R5, verified) — fallback ----------------
__global__ void FP8FL_gemm(const short* __restrict__ A, const short* __restrict__ B,
                           const float* __restrict__ bias, float* __restrict__ C,
                           int M, int N, int K) {
    __shared__ short As[TILE * BKK];
    __shared__ short Bs[TILE * BKK];

    const int tid  = threadIdx.x;
    const int lane = tid & 63;
    const int wid  = tid >> 6;

    const int nwg = gridDim.x;
    const int bid = blockIdx.x;
    const int wg  = (nwg % 8 == 0) ? (bid % 8) * (nwg / 8) + (bid / 8) : bid;

    const int tiles_n = N / TILE;
    const long row0 = (long)(wg / tiles_n) * TILE;
    const long col0 = (long)(wg % tiles_n) * TILE;

    const int wm = wid >> 1, wn = wid & 1;

    f32x4 acc[4][4];
#pragma unroll
    for (int i = 0; i < 4; ++i)
#pragma unroll
        for (int j = 0; j < 4; ++j) acc[i][j] = (f32x4){0.f, 0.f, 0.f, 0.f};

    const int rl = lane & 15;
    const int g  = lane >> 4;

    for (int k0 = 0; k0 < K; k0 += BKK) {
        __syncthreads();
#pragma unroll
        for (int i = 0; i < 4; ++i) {
            int c  = i * 256 + tid;
            int r  = c >> 3;
            int ls = c & 7;
            const short* ga = A + ((size_t)(row0 + r) * K + k0 + ls * 8);
            const short* gb = B + ((size_t)(col0 + r) * K + k0 + ls * 8);
            int ldsoff = (i * 256 + wid * 64) * 16;
            __builtin_amdgcn_global_load_lds(GLOBAL_AS(ga), LDS_AS((char*)As + ldsoff), 16, 0, 0);
            __builtin_amdgcn_global_load_lds(GLOBAL_AS(gb), LDS_AS((char*)Bs + ldsoff), 16, 0, 0);
        }
        __syncthreads();

#pragma unroll
        for (int kk = 0; kk < 2; ++kk) {
            bfrag8 af[4], bfr[4];
            const int lsk = kk * 4 + g;
#pragma unroll
            for (int m = 0; m < 4; ++m) {
                int r  = wm * 64 + m * 16 + rl;
                af[m] = *(const bfrag8*)&As[r * 64 + lsk * 8];
            }
#pragma unroll
            for (int n = 0; n < 4; ++n) {
                int r  = wn * 64 + n * 16 + rl;
                bfr[n] = *(const bfrag8*)&Bs[r * 64 + lsk * 8];
            }
#pragma unroll
            for (int m = 0; m < 4; ++m)
#pragma unroll
                for (int n = 0; n < 4; ++n)
                    acc[m][n] = __builtin_amdgcn_mfma_f32_16x16x32_bf16(af[m], bfr[n], acc[m][n], 0, 0, 0);
        }
    }

    float bv[4];
#pragma unroll
    for (int n = 0; n < 4; ++n) bv[n] = bias[col0 + wn * 64 + n * 16 + rl];
#pragma unroll
    for (int m = 0; m < 4; ++m) {
#pragma unroll
        for (int j = 0; j < 4; ++j) {
            long r = row0 + wm * 64 + m * 16 + g * 4 + j;
            float* cp = C + r * (long)N + col0 + wn * 64 + rl;
#pragma unroll
            for (int n = 0; n < 4; ++n) cp[n * 16] = acc[m][n][j] + bv[n];
        }
    }
}

// Fused GEMM (ws too small): reads x (f32) and W (bf16/f32) directly. R5-verified path.
__global__ void FP8FL_gemm_fused(const float* __restrict__ X, const void* __restrict__ W,
                                 const float* __restrict__ scale_p,
                                 const float* __restrict__ bias, float* __restrict__ C,
                                 int M, int N, int K) {
    __shared__ short As[TILE * BKK];
    __shared__ short Bs[TILE * BKK];
    __shared__ int sdt;

    const int tid  = threadIdx.x;
    const int lane = tid & 63;
    const int wid  = tid >> 6;

    if (tid == 0) sdt = detect_w_f32(W);
    __syncthreads();
    const int wdt = sdt;
    const float s = scale_p[0];

    const int nwg = gridDim.x;
    const int bid = blockIdx.x;
    const int wg  = (nwg % 8 == 0) ? (bid % 8) * (nwg / 8) + (bid / 8) : bid;

    const int tiles_n = N / TILE;
    const long row0 = (long)(wg / tiles_n) * TILE;
    const long col0 = (long)(wg % tiles_n) * TILE;

    const int wm = wid >> 1, wn = wid & 1;

    f32x4 acc[4][4];
#pragma unroll
    for (int i = 0; i < 4; ++i)
#pragma unroll
        for (int j = 0; j < 4; ++j) acc[i][j] = (f32x4){0.f, 0.f, 0.f, 0.f};

    const int rl = lane & 15;
    const int g  = lane >> 4;

    for (int k0 = 0; k0 < K; k0 += BKK) {
        s8v va[4], vb[4];
#pragma unroll
        for (int i = 0; i < 4; ++i) {
            int c  = i * 256 + tid;
            int r  = c >> 3;
            int ls = c & 7;
            {
                const float* xp = X + ((size_t)(row0 + r) * K + k0 + ls * 8);
                float4 a = *(const float4*)xp;
                float4 b = *(const float4*)(xp + 4);
                s8v t;
                t[0] = (short)f2bf(a.x); t[1] = (short)f2bf(a.y);
                t[2] = (short)f2bf(a.z); t[3] = (short)f2bf(a.w);
                t[4] = (short)f2bf(b.x); t[5] = (short)f2bf(b.y);
                t[6] = (short)f2bf(b.z); t[7] = (short)f2bf(b.w);
                va[i] = t;
            }
            {
                size_t off = (size_t)(col0 + r) * K + k0 + ls * 8;
                s8v t;
                if (wdt) {
                    const float* wp = (const float*)W + off;
                    float4 a = *(const float4*)wp;
                    float4 b = *(const float4*)(wp + 4);
                    t[0] = (short)f2bf(a.x * s); t[1] = (short)f2bf(a.y * s);
                    t[2] = (short)f2bf(a.z * s); t[3] = (short)f2bf(a.w * s);
                    t[4] = (short)f2bf(b.x * s); t[5] = (short)f2bf(b.y * s);
                    t[6] = (short)f2bf(b.z * s); t[7] = (short)f2bf(b.w * s);
                } else {
                    const unsigned short* wp = (const unsigned short*)W + off;
                    s8v v = *(const s8v*)wp;
#pragma unroll
                    for (int j = 0; j < 8; ++j)
                        t[j] = (short)f2bf(bf2f((unsigned short)v[j]) * s);
                }
                vb[i] = t;
            }
        }
        __syncthreads();
#pragma unroll
        for (int i = 0; i < 4; ++i) {
            int c = i * 256 + tid;
            *(s8v*)((char*)As + (size_t)c * 16) = va[i];
            *(s8v*)((char*)Bs + (size_t)c * 16) = vb[i];
        }
        __syncthreads();

#pragma unroll
        for (int kk = 0; kk < 2; ++kk) {
            bfrag8 af[4], bfr[4];
            const int lsk = kk * 4 + g;
#pragma unroll
            for (int m = 0; m < 4; ++m) {
                int r  = wm * 64 + m * 16 + rl;
                af[m] = *(const bfrag8*)&As[r * 64 + lsk * 8];
            }
#pragma unroll
            for (int n = 0; n < 4; ++n) {
                int r  = wn * 64 + n * 16 + rl;
                bfr[n] = *(const bfrag8*)&Bs[r * 64 + lsk * 8];
            }
#pragma unroll
            for (int m = 0; m < 4; ++m)
#pragma unroll
                for (int n = 0; n < 4; ++n)
                    acc[m][n] = __builtin_amdgcn_mfma_f32_16x16x32_bf16(af[m], bfr[n], acc[m][n], 0, 0, 0);
        }
    }

    float bv[4];
#pragma unroll
    for (int n = 0; n < 4; ++n) bv[n] = bias[col0 + wn * 64 + n * 16 + rl];
#pragma unroll
    for (int m = 0; m < 4; ++m) {
#pragma unroll
        for (int j = 0; j < 4; ++j) {
            long r = row0 + wm * 64 + m * 16 + g * 4 + j;
            float* cp = C + r * (long)N + col0 + wn * 64 + rl;
#pragma unroll
            for (int n = 0; n < 4; ++n) cp[n * 16] = acc[m][n][j] + bv[n];
        }
    }
}

// Last-resort fallback (odd dims).
__global__ void FP8FL_naive(const float* __restrict__ x, const void* __restrict__ w,
                            const float* __restrict__ scale_p, const float* __restrict__ bias,
                            float* __restrict__ out, int M, int N, int K) {
    __shared__ int sdt;
    if (threadIdx.x == 0) sdt = detect_w_f32(w);
    __syncthreads();
    long o = (long)blockIdx.x * blockDim.x + threadIdx.x;
    if (o >= (long)M * N) return;
    int m = (int)(o / N), n = (int)(o % N);
    const float* xr = x + (size_t)m * K;
    float acc = 0.f;
    if (sdt) {
        const float* wr = (const float*)w + (size_t)n * K;
        for (int k = 0; k < K; ++k) acc += xr[k] * wr[k];
    } else {
        const unsigned short* wr = (const unsigned short*)w + (size_t)n * K;
        for (int k = 0; k < K; ++k) acc += xr[k] * bf2f(wr[k]);
    }
    out[o] = acc * scale_p[0] + bias[n];
}

extern "C" void kernel_launch(void* const* d_in, const int* in_sizes, int n_in,
                              void* d_out, int out_size, void* d_ws, size_t ws_size,
                              hipStream_t stream) {
    const float* x     = (const float*)d_in[0];
    const void*  w     = d_in[1];
    const float* scale = (const float*)d_in[2];
    const float* bias  = (const float*)d_in[3];
    float*       out   = (float*)d_out;

    const int N = in_sizes[3];
    const int K = in_sizes[1] / N;
    const int M = in_sizes[0] / K;

    const size_t need = (size_t)M * K * 2 + (size_t)N * K * 2;
    const bool ws_ok   = ws_size >= need;
    const bool dims256 = (M % BM256 == 0) && (N % BN256 == 0) && (K % BKK == 0) && (K / BKK >= 2);
    const bool dims128 = (M % TILE == 0) && (N % TILE == 0) && (K % BKK == 0);

    if (ws_ok && (dims256 || dims128)) {
        short* xb = (short*)d_ws;
        short* wb = (short*)((char*)d_ws + (size_t)M * K * 2);
        long nx = (long)M * K;
        long nw = (long)N * K;
        FP8FL_cvt_x<<<(int)((nx / 8 + 255) / 256), 256, 0, stream>>>(x, xb, nx);
        FP8FL_cvt_w<<<(int)((nw / 8 + 255) / 256), 256, 0, stream>>>(w, wb, scale, nw);
        if (dims256) {
            int grid = (M / BM256) * (N / BN256);
            FP8FL_gemm256<<<grid, 512, 0, stream>>>(xb, wb, bias, out, M, N, K);
        } else {
            int grid = (M / TILE) * (N / TILE);
            FP8FL_gemm<<<grid, 256, 0, stream>>>(xb, wb, bias, out, M, N, K);
        }
    } else if (dims128) {
        int grid = (M / TILE) * (N / TILE);
        FP8FL_gemm_fused<<<grid, 256, 0, stream>>>(x, w, scale, bias, out, M, N, K);
    } else {
        long total = (long)M * N;
        FP8FL_naive<<<(int)((total + 255) / 256), 256, 0, stream>>>(x, w, scale, bias, out, M, N, K);
    }
}

// Round 14
// 271.653 us; speedup vs baseline: 1.2201x; 1.0642x over previous
//
#include <hip/hip_runtime.h>

// FP8FrozenLinear: out = x @ (dequant(W)*scale)^T + bias   (W shipped as bf16/f32)
// M=8192, K=4096, N=4096.
// Round 14: FINAL — exact revert to Round 7 (best measured: 274.85 µs total,
// GEMM 260 µs ≈ 1.06 PF, MfmaUtil 47%, bank conflicts 0).
// 256x256 tile, BK=64, 2 LDS buffers, one phase/K-tile: all 24 frag ds_reads
// issued up-front (slab-1 drains under slab-0 MFMA via compiler partial
// lgkmcnt), next-tile global_load_lds prefetch, one __syncthreads per tile.
// T2 both-sides slot swizzle (rule #21) + bijective XCD swizzle.
// Seven schedule variants (R5-R13) all plateau at 44-47% MfmaUtil: per-tile
// MFMA demand (~2480 cyc) + LDS-frag demand (~2300 cyc) serialize at the
// register-forced 2 waves/SIMD; this is the plain-HIP best of that family.

#define TILE 128
#define BKK  64
#define BM256 256
#define BN256 256

typedef __attribute__((ext_vector_type(8))) __bf16 bfrag8;
typedef __attribute__((ext_vector_type(4))) float  f32x4;
typedef __attribute__((ext_vector_type(8))) short  s8v;

#define GLOBAL_AS(p) ((const __attribute__((address_space(1))) void*)(p))
#define LDS_AS(p)    ((__attribute__((address_space(3))) void*)(p))

__device__ inline unsigned short f2bf(float f) {
    union { float f; unsigned u; } v; v.f = f;
    unsigned r = v.u + 0x7FFFu + ((v.u >> 16) & 1u);   // RNE
    return (unsigned short)(r >> 16);
}
__device__ inline float bf2f(unsigned short u) {
    union { unsigned u; float f; } v; v.u = ((unsigned)u) << 16;
    return v.f;
}

// W storage dtype: f32 storage of fp8-grid values => even uint16s all zero.
__device__ inline int detect_w_f32(const void* w) {
    const unsigned short* u = (const unsigned short*)w;
    unsigned nz = 0;
#pragma unroll
    for (int i = 0; i < 64; ++i) nz |= u[2 * i];
    return nz == 0 ? 1 : 0;
}

__global__ void FP8FL_cvt_x(const float* __restrict__ x, short* __restrict__ xb, long n) {
    long i = ((long)blockIdx.x * blockDim.x + threadIdx.x) * 8;
    if (i >= n) return;
    float4 a = *(const float4*)(x + i);
    float4 b = *(const float4*)(x + i + 4);
    s8v r;
    r[0] = (short)f2bf(a.x); r[1] = (short)f2bf(a.y);
    r[2] = (short)f2bf(a.z); r[3] = (short)f2bf(a.w);
    r[4] = (short)f2bf(b.x); r[5] = (short)f2bf(b.y);
    r[6] = (short)f2bf(b.z); r[7] = (short)f2bf(b.w);
    *(s8v*)(xb + i) = r;
}

__global__ void FP8FL_cvt_w(const void* __restrict__ w, short* __restrict__ wb,
                            const float* __restrict__ scale_p, long n) {
    __shared__ int sdt;
    if (threadIdx.x == 0) sdt = detect_w_f32(w);
    __syncthreads();
    long i = ((long)blockIdx.x * blockDim.x + threadIdx.x) * 8;
    if (i >= n) return;
    const float s = scale_p[0];
    s8v r;
    if (sdt) {
        const float* wf = (const float*)w;
        float4 a = *(const float4*)(wf + i);
        float4 b = *(const float4*)(wf + i + 4);
        r[0] = (short)f2bf(a.x * s); r[1] = (short)f2bf(a.y * s);
        r[2] = (short)f2bf(a.z * s); r[3] = (short)f2bf(a.w * s);
        r[4] = (short)f2bf(b.x * s); r[5] = (short)f2bf(b.y * s);
        r[6] = (short)f2bf(b.z * s); r[7] = (short)f2bf(b.w * s);
    } else {
        const unsigned short* wu = (const unsigned short*)w;
        s8v v = *(const s8v*)(wu + i);
#pragma unroll
        for (int j = 0; j < 8; ++j)
            r[j] = (short)f2bf(bf2f((unsigned short)v[j]) * s);
    }
    *(s8v*)(wb + i) = r;
}

// ---------------- 256x256 GEMM, 1 phase / K-tile (R7) ----------------
// LDS: A slab p: d*65536 + p*16384 ; B slab p: d*65536 + 32768 + p*16384.
// Slab = [256 rows][4 slots x 16B], phys slot = logical ^ ((row>>1)&3),
// staged linearly with inverse-swizzled global source (rule #21).
__device__ inline void stage_tile256(const short* __restrict__ A, const short* __restrict__ B,
                                     long row0, long col0, int K, int kc,
                                     char* __restrict__ lds, int d, int wid, int lane) {
#pragma unroll
    for (int p = 0; p < 2; ++p) {
        char* Asl = lds + d * 65536 + p * 16384;
        char* Bsl = lds + d * 65536 + 32768 + p * 16384;
        int kk = kc + p * 32;
#pragma unroll
        for (int i = 0; i < 2; ++i) {
            int pc = i * 512 + wid * 64 + lane;
            int r  = pc >> 2;
            int j  = (pc & 3) ^ ((r >> 1) & 3);
            const short* ga = A + (size_t)(row0 + r) * K + kk + j * 8;
            const short* gb = B + (size_t)(col0 + r) * K + kk + j * 8;
            char* da = Asl + (i * 512 + wid * 64) * 16;   // wave-uniform base
            char* db = Bsl + (i * 512 + wid * 64) * 16;
            __builtin_amdgcn_global_load_lds(GLOBAL_AS(ga), LDS_AS(da), 16, 0, 0);
            __builtin_amdgcn_global_load_lds(GLOBAL_AS(gb), LDS_AS(db), 16, 0, 0);
        }
    }
}

__global__ __launch_bounds__(512, 2)
void FP8FL_gemm256(const short* __restrict__ A, const short* __restrict__ B,
                   const float* __restrict__ bias, float* __restrict__ C,
                   int M, int N, int K) {
    __shared__ char lds[131072];

    const int tid  = threadIdx.x;
    const int lane = tid & 63;
    const int wid  = tid >> 6;

    const int nwg = gridDim.x;
    const int bid = blockIdx.x;
    const int wg  = (nwg % 8 == 0) ? (bid % 8) * (nwg / 8) + (bid / 8) : bid;

    const int tiles_n = N / BN256;
    const long row0 = (long)(wg / tiles_n) * BM256;
    const long col0 = (long)(wg % tiles_n) * BN256;

    const int wm = wid >> 2, wn = wid & 3;      // 2x4 wave grid, 128x64 out each
    const int rl = lane & 15, g = lane >> 4;

    f32x4 acc[8][4];
#pragma unroll
    for (int m = 0; m < 8; ++m)
#pragma unroll
        for (int n = 0; n < 4; ++n) acc[m][n] = (f32x4){0.f, 0.f, 0.f, 0.f};

    const int NT = K / BKK;

    // Prologue: stage tile 0 into buffer 0; full drain + barrier.
    stage_tile256(A, B, row0, col0, K, 0, lds, 0, wid, lane);
    __syncthreads();

    for (int t = 0; t < NT; ++t) {
        const int d = t & 1;
        const char* base = lds + d * 65536;

        // Issue ALL fragment reads (both slabs) up front: slab-1 reads drain
        // under slab-0 MFMA via compiler partial lgkmcnt.
        bfrag8 af[2][8], bf[2][4];
#pragma unroll
        for (int p = 0; p < 2; ++p) {
            const char* Asl = base + p * 16384;
            const char* Bsl = base + 32768 + p * 16384;
#pragma unroll
            for (int m = 0; m < 8; ++m) {
                int r  = wm * 128 + m * 16 + rl;
                int sl = g ^ ((r >> 1) & 3);
                af[p][m] = *(const bfrag8*)(Asl + (r * 4 + sl) * 16);
            }
#pragma unroll
            for (int n = 0; n < 4; ++n) {
                int r  = wn * 64 + n * 16 + rl;
                int sl = g ^ ((r >> 1) & 3);
                bf[p][n] = *(const bfrag8*)(Bsl + (r * 4 + sl) * 16);
            }
        }

        // Prefetch next tile into the other buffer (full-tile vmcnt slack).
        if (t + 1 < NT)
            stage_tile256(A, B, row0, col0, K, (t + 1) * BKK, lds, d ^ 1, wid, lane);

        __builtin_amdgcn_s_setprio(1);
#pragma unroll
        for (int p = 0; p < 2; ++p)
#pragma unroll
            for (int m = 0; m < 8; ++m)
#pragma unroll
                for (int n = 0; n < 4; ++n)
                    acc[m][n] = __builtin_amdgcn_mfma_f32_16x16x32_bf16(af[p][m], bf[p][n], acc[m][n], 0, 0, 0);
        __builtin_amdgcn_s_setprio(0);

        // One barrier per tile: drains vmcnt(0) (stage done) + syncs waves.
        __syncthreads();
    }

    // Epilogue: C/D layout col = lane&15, row = (lane>>4)*4 + reg  [m89/m91]
    float bv[4];
#pragma unroll
    for (int n = 0; n < 4; ++n) bv[n] = bias[col0 + wn * 64 + n * 16 + rl];
#pragma unroll
    for (int m = 0; m < 8; ++m) {
#pragma unroll
        for (int jj = 0; jj < 4; ++jj) {
            long r = row0 + wm * 128 + m * 16 + g * 4 + jj;
            float* cp = C + r * (long)N + col0 + wn * 64 + rl;
#pragma unroll
            for (int n = 0; n < 4; ++n) cp[n * 16] = acc[m][n][jj] + bv[n];
        }
    }
}

// ---------------- m97-style 128^2 GEMM (R5, verified) — fallback ----------------
__global__ void FP8FL_gemm(const short* __restrict__ A, const short* __restrict__ B,
                           const float* __restrict__ bias, float* __restrict__ C,
                           int M, int N, int K) {
    __shared__ short As[TILE * BKK];
    __shared__ short Bs[TILE * BKK];

    const int tid  = threadIdx.x;
    const int lane = tid & 63;
    const int wid  = tid >> 6;

    const int nwg = gridDim.x;
    const int bid = blockIdx.x;
    const int wg  = (nwg % 8 == 0) ? (bid % 8) * (nwg / 8) + (bid / 8) : bid;

    const int tiles_n = N / TILE;
    const long row0 = (long)(wg / tiles_n) * TILE;
    const long col0 = (long)(wg % tiles_n) * TILE;

    const int wm = wid >> 1, wn = wid & 1;

    f32x4 acc[4][4];
#pragma unroll
    for (int i = 0; i < 4; ++i)
#pragma unroll
        for (int j = 0; j < 4; ++j) acc[i][j] = (f32x4){0.f, 0.f, 0.f, 0.f};

    const int rl = lane & 15;
    const int g  = lane >> 4;

    for (int k0 = 0; k0 < K; k0 += BKK) {
        __syncthreads();
#pragma unroll
        for (int i = 0; i < 4; ++i) {
            int c  = i * 256 + tid;
            int r  = c >> 3;
            int ls = c & 7;
            const short* ga = A + ((size_t)(row0 + r) * K + k0 + ls * 8);
            const short* gb = B + ((size_t)(col0 + r) * K + k0 + ls * 8);
            int ldsoff = (i * 256 + wid * 64) * 16;
            __builtin_amdgcn_global_load_lds(GLOBAL_AS(ga), LDS_AS((char*)As + ldsoff), 16, 0, 0);
            __builtin_amdgcn_global_load_lds(GLOBAL_AS(gb), LDS_AS((char*)Bs + ldsoff), 16, 0, 0);
        }
        __syncthreads();

#pragma unroll
        for (int kk = 0; kk < 2; ++kk) {
            bfrag8 af[4], bfr[4];
            const int lsk = kk * 4 + g;
#pragma unroll
            for (int m = 0; m < 4; ++m) {
                int r  = wm * 64 + m * 16 + rl;
                af[m] = *(const bfrag8*)&As[r * 64 + lsk * 8];
            }
#pragma unroll
            for (int n = 0; n < 4; ++n) {
                int r  = wn * 64 + n * 16 + rl;
                bfr[n] = *(const bfrag8*)&Bs[r * 64 + lsk * 8];
            }
#pragma unroll
            for (int m = 0; m < 4; ++m)
#pragma unroll
                for (int n = 0; n < 4; ++n)
                    acc[m][n] = __builtin_amdgcn_mfma_f32_16x16x32_bf16(af[m], bfr[n], acc[m][n], 0, 0, 0);
        }
    }

    float bv[4];
#pragma unroll
    for (int n = 0; n < 4; ++n) bv[n] = bias[col0 + wn * 64 + n * 16 + rl];
#pragma unroll
    for (int m = 0; m < 4; ++m) {
#pragma unroll
        for (int j = 0; j < 4; ++j) {
            long r = row0 + wm * 64 + m * 16 + g * 4 + j;
            float* cp = C + r * (long)N + col0 + wn * 64 + rl;
#pragma unroll
            for (int n = 0; n < 4; ++n) cp[n * 16] = acc[m][n][j] + bv[n];
        }
    }
}

// Fused GEMM (ws too small): reads x (f32) and W (bf16/f32) directly. R5-verified path.
__global__ void FP8FL_gemm_fused(const float* __restrict__ X, const void* __restrict__ W,
                                 const float* __restrict__ scale_p,
                                 const float* __restrict__ bias, float* __restrict__ C,
                                 int M, int N, int K) {
    __shared__ short As[TILE * BKK];
    __shared__ short Bs[TILE * BKK];
    __shared__ int sdt;

    const int tid  = threadIdx.x;
    const int lane = tid & 63;
    const int wid  = tid >> 6;

    if (tid == 0) sdt = detect_w_f32(W);
    __syncthreads();
    const int wdt = sdt;
    const float s = scale_p[0];

    const int nwg = gridDim.x;
    const int bid = blockIdx.x;
    const int wg  = (nwg % 8 == 0) ? (bid % 8) * (nwg / 8) + (bid / 8) : bid;

    const int tiles_n = N / TILE;
    const long row0 = (long)(wg / tiles_n) * TILE;
    const long col0 = (long)(wg % tiles_n) * TILE;

    const int wm = wid >> 1, wn = wid & 1;

    f32x4 acc[4][4];
#pragma unroll
    for (int i = 0; i < 4; ++i)
#pragma unroll
        for (int j = 0; j < 4; ++j) acc[i][j] = (f32x4){0.f, 0.f, 0.f, 0.f};

    const int rl = lane & 15;
    const int g  = lane >> 4;

    for (int k0 = 0; k0 < K; k0 += BKK) {
        s8v va[4], vb[4];
#pragma unroll
        for (int i = 0; i < 4; ++i) {
            int c  = i * 256 + tid;
            int r  = c >> 3;
            int ls = c & 7;
            {
                const float* xp = X + ((size_t)(row0 + r) * K + k0 + ls * 8);
                float4 a = *(const float4*)xp;
                float4 b = *(const float4*)(xp + 4);
                s8v t;
                t[0] = (short)f2bf(a.x); t[1] = (short)f2bf(a.y);
                t[2] = (short)f2bf(a.z); t[3] = (short)f2bf(a.w);
                t[4] = (short)f2bf(b.x); t[5] = (short)f2bf(b.y);
                t[6] = (short)f2bf(b.z); t[7] = (short)f2bf(b.w);
                va[i] = t;
            }
            {
                size_t off = (size_t)(col0 + r) * K + k0 + ls * 8;
                s8v t;
                if (wdt) {
                    const float* wp = (const float*)W + off;
                    float4 a = *(const float4*)wp;
                    float4 b = *(const float4*)(wp + 4);
                    t[0] = (short)f2bf(a.x * s); t[1] = (short)f2bf(a.y * s);
                    t[2] = (short)f2bf(a.z * s); t[3] = (short)f2bf(a.w * s);
                    t[4] = (short)f2bf(b.x * s); t[5] = (short)f2bf(b.y * s);
                    t[6] = (short)f2bf(b.z * s); t[7] = (short)f2bf(b.w * s);
                } else {
                    const unsigned short* wp = (const unsigned short*)W + off;
                    s8v v = *(const s8v*)wp;
#pragma unroll
                    for (int j = 0; j < 8; ++j)
                        t[j] = (short)f2bf(bf2f((unsigned short)v[j]) * s);
                }
                vb[i] = t;
            }
        }
        __syncthreads();
#pragma unroll
        for (int i = 0; i < 4; ++i) {
            int c = i * 256 + tid;
            *(s8v*)((char*)As + (size_t)c * 16) = va[i];
            *(s8v*)((char*)Bs + (size_t)c * 16) = vb[i];
        }
        __syncthreads();

#pragma unroll
        for (int kk = 0; kk < 2; ++kk) {
            bfrag8 af[4], bfr[4];
            const int lsk = kk * 4 + g;
#pragma unroll
            for (int m = 0; m < 4; ++m) {
                int r  = wm * 64 + m * 16 + rl;
                af[m] = *(const bfrag8*)&As[r * 64 + lsk * 8];
            }
#pragma unroll
            for (int n = 0; n < 4; ++n) {
                int r  = wn * 64 + n * 16 + rl;
                bfr[n] = *(const bfrag8*)&Bs[r * 64 + lsk * 8];
            }
#pragma unroll
            for (int m = 0; m < 4; ++m)
#pragma unroll
                for (int n = 0; n < 4; ++n)
                    acc[m][n] = __builtin_amdgcn_mfma_f32_16x16x32_bf16(af[m], bfr[n], acc[m][n], 0, 0, 0);
        }
    }

    float bv[4];
#pragma unroll
    for (int n = 0; n < 4; ++n) bv[n] = bias[col0 + wn * 64 + n * 16 + rl];
#pragma unroll
    for (int m = 0; m < 4; ++m) {
#pragma unroll
        for (int j = 0; j < 4; ++j) {
            long r = row0 + wm * 64 + m * 16 + g * 4 + j;
            float* cp = C + r * (long)N + col0 + wn * 64 + rl;
#pragma unroll
            for (int n = 0; n < 4; ++n) cp[n * 16] = acc[m][n][j] + bv[n];
        }
    }
}

// Last-resort fallback (odd dims).
__global__ void FP8FL_naive(const float* __restrict__ x, const void* __restrict__ w,
                            const float* __restrict__ scale_p, const float* __restrict__ bias,
                            float* __restrict__ out, int M, int N, int K) {
    __shared__ int sdt;
    if (threadIdx.x == 0) sdt = detect_w_f32(w);
    __syncthreads();
    long o = (long)blockIdx.x * blockDim.x + threadIdx.x;
    if (o >= (long)M * N) return;
    int m = (int)(o / N), n = (int)(o % N);
    const float* xr = x + (size_t)m * K;
    float acc = 0.f;
    if (sdt) {
        const float* wr = (const float*)w + (size_t)n * K;
        for (int k = 0; k < K; ++k) acc += xr[k] * wr[k];
    } else {
        const unsigned short* wr = (const unsigned short*)w + (size_t)n * K;
        for (int k = 0; k < K; ++k) acc += xr[k] * bf2f(wr[k]);
    }
    out[o] = acc * scale_p[0] + bias[n];
}

extern "C" void kernel_launch(void* const* d_in, const int* in_sizes, int n_in,
                              void* d_out, int out_size, void* d_ws, size_t ws_size,
                              hipStream_t stream) {
    const float* x     = (const float*)d_in[0];
    const void*  w     = d_in[1];
    const float* scale = (const float*)d_in[2];
    const float* bias  = (const float*)d_in[3];
    float*       out   = (float*)d_out;

    const int N = in_sizes[3];
    const int K = in_sizes[1] / N;
    const int M = in_sizes[0] / K;

    const size_t need = (size_t)M * K * 2 + (size_t)N * K * 2;
    const bool ws_ok   = ws_size >= need;
    const bool dims256 = (M % BM256 == 0) && (N % BN256 == 0) && (K % BKK == 0);
    const bool dims128 = (M % TILE == 0) && (N % TILE == 0) && (K % BKK == 0);

    if (ws_ok && (dims256 || dims128)) {
        short* xb = (short*)d_ws;
        short* wb = (short*)((char*)d_ws + (size_t)M * K * 2);
        long nx = (long)M * K;
        long nw = (long)N * K;
        FP8FL_cvt_x<<<(int)((nx / 8 + 255) / 256), 256, 0, stream>>>(x, xb, nx);
        FP8FL_cvt_w<<<(int)((nw / 8 + 255) / 256), 256, 0, stream>>>(w, wb, scale, nw);
        if (dims256) {
            int grid = (M / BM256) * (N / BN256);
            FP8FL_gemm256<<<grid, 512, 0, stream>>>(xb, wb, bias, out, M, N, K);
        } else {
            int grid = (M / TILE) * (N / TILE);
            FP8FL_gemm<<<grid, 256, 0, stream>>>(xb, wb, bias, out, M, N, K);
        }
    } else if (dims128) {
        int grid = (M / TILE) * (N / TILE);
        FP8FL_gemm_fused<<<grid, 256, 0, stream>>>(x, w, scale, bias, out, M, N, K);
    } else {
        long total = (long)M * N;
        FP8FL_naive<<<(int)((total + 255) / 256), 256, 0, stream>>>(x, w, scale, bias, out, M, N, K);
    }
}